// Round 5
// baseline (281.280 us; speedup 1.0000x reference)
//
#include <hip/hip_runtime.h>
#include <stdint.h>

// Shapes fixed by the reference setup_inputs()
#define B 8
#define N 256
#define D 256
#define O 256
#define R 512
#define E 8192
#define NSW 8192              // persistent sample waves (2048 blocks x 4)
#define F32_TINY 1.17549435e-38f

// ---------------- threefry2x32, key = (0, 42) --------------------------------
__device__ __forceinline__ void threefry2x32_k42(uint32_t x0, uint32_t x1,
                                                 uint32_t& o0, uint32_t& o1) {
  const uint32_t ks0 = 0u;
  const uint32_t ks1 = 42u;
  const uint32_t ks2 = 0u ^ 42u ^ 0x1BD11BDAu;
  x0 += ks0; x1 += ks1;
#define TF_R(r) { x0 += x1; x1 = (x1 << (r)) | (x1 >> (32 - (r))); x1 ^= x0; }
  TF_R(13) TF_R(15) TF_R(26) TF_R(6)
  x0 += ks1; x1 += ks2 + 1u;
  TF_R(17) TF_R(29) TF_R(16) TF_R(24)
  x0 += ks2; x1 += ks0 + 2u;
  TF_R(13) TF_R(15) TF_R(26) TF_R(6)
  x0 += ks0; x1 += ks1 + 3u;
  TF_R(17) TF_R(29) TF_R(16) TF_R(24)
  x0 += ks1; x1 += ks2 + 4u;
  TF_R(13) TF_R(15) TF_R(26) TF_R(6)
  x0 += ks2; x1 += ks0 + 5u;
#undef TF_R
  o0 = x0; o1 = x1;
}

__device__ __forceinline__ float gumbel_from_bits_f(float f) {
  float u = (f == 0.0f) ? F32_TINY : f;
  return -logf(-logf(u));
}

// ---------------- prep: transpose + Wr GEMM + x2 + wcount=0 ------------------
// blocks 0-255: 64x64 transpose tiles (128 score, 128 f2e)
// blocks 256-767: Wr row (d-split halves)
// blocks 768-771: x2 rows
__global__ __launch_bounds__(512) void prep_kernel(const float* __restrict__ score,
                                                   float* __restrict__ scoreT,
                                                   const float* __restrict__ f2e,
                                                   float* __restrict__ f2eT,
                                                   const float* __restrict__ relf,
                                                   const float* __restrict__ Wk,
                                                   const float* __restrict__ bk,
                                                   float* __restrict__ Wr,
                                                   float* __restrict__ x2,
                                                   int* __restrict__ wcount) {
  int blk = blockIdx.x;
  int tid = threadIdx.x;
  if (blk == 0 && tid == 0) *wcount = 0;
  if (blk < 256) {
    __shared__ float tile[64][65];
    const float* src = (blk < 128) ? score : f2e;
    float* dst = (blk < 128) ? scoreT : f2eT;
    int b7 = blk & 127;
    int bb = b7 >> 4, t = b7 & 15, ti = t >> 2, tj = t & 3;
    size_t base = (size_t)bb * 65536;
    int c = tid & 63, r8 = tid >> 6;          // r8 in [0,8)
#pragma unroll
    for (int rr = 0; rr < 64; rr += 8) {
      int row = rr + r8;
      tile[row][c] = src[base + (size_t)(ti * 64 + row) * 256 + tj * 64 + c];
    }
    __syncthreads();
#pragma unroll
    for (int rr = 0; rr < 64; rr += 8) {
      int row = rr + r8;
      dst[base + (size_t)(tj * 64 + row) * 256 + ti * 64 + c] = tile[c][row];
    }
  } else if (blk < 768) {
    // Wr[r,:] = relf[r,:] @ Wk + bk ; d-split across thread halves
    int r = blk - 256;
    int o = tid & 255, kh = tid >> 8;
    __shared__ float rrow[256];
    __shared__ float part[2][256];
    if (tid < 256) rrow[tid] = relf[(size_t)r * 256 + tid];
    __syncthreads();
    const float* wp = Wk + (size_t)kh * 128 * 256 + o;
    const float* rp = rrow + kh * 128;
    float accA = 0.f, accB = 0.f;
    float nb[8];
#pragma unroll
    for (int j = 0; j < 8; ++j) nb[j] = wp[(size_t)j * 256];
    for (int d = 0; d < 128; d += 8) {
      float bb[8];
#pragma unroll
      for (int j = 0; j < 8; ++j) bb[j] = nb[j];
      if (d + 8 < 128) {
#pragma unroll
        for (int j = 0; j < 8; ++j) nb[j] = wp[(size_t)(d + 8 + j) * 256];
      }
#pragma unroll
      for (int j = 0; j < 8; j += 2) {
        accA += rp[d + j] * bb[j];
        accB += rp[d + j + 1] * bb[j + 1];
      }
    }
    part[kh][o] = accA + accB;
    __syncthreads();
    if (kh == 0) Wr[(size_t)r * 256 + o] = part[0][o] + part[1][o] + bk[o];
  } else {
    // x2 rows (f64 chain, one row per thread)
    int i = (blk - 768) * 512 + tid;          // [0, 2048)
    const float4* p = (const float4*)(f2e + (size_t)i * D);
    double s = 0.0;
    for (int d = 0; d < D / 4; ++d) {
      float4 v = p[d];
      s += (double)v.x * v.x; s += (double)v.y * v.y;
      s += (double)v.z * v.z; s += (double)v.w * v.w;
    }
    x2[i] = (float)s;
  }
}

// ---------------- sim + logits + laux; 4 rows/block, 512 threads -------------
__global__ __launch_bounds__(512) void sim_kernel(const float* __restrict__ f2e,
                                                  const float* __restrict__ f2eT,
                                                  const float* __restrict__ x2,
                                                  float* __restrict__ sim,
                                                  float* __restrict__ logits,
                                                  float* __restrict__ laux) {
  int bn0 = blockIdx.x * 4;    // 4 consecutive (b,n) rows, same b
  int b = bn0 >> 8;
  int tid = threadIdx.x;
  int col = tid & 255, half = tid >> 8;       // half: rows {0,1} or {2,3}
  __shared__ float arow[4][256];
  __shared__ float nbuf[4][256];
  {
    const float2* src = (const float2*)(f2e + (size_t)bn0 * 256);
    float2 v = src[tid];
    int rr = tid >> 7, cc = (tid & 127) * 2;
    arow[rr][cc] = v.x; arow[rr][cc + 1] = v.y;
  }
  __syncthreads();
  int r0 = half * 2, r1 = r0 + 1;
  const float* fT = f2eT + (size_t)b * 65536 + col;
  float a0A = 0.f, a0B = 0.f, a1A = 0.f, a1B = 0.f;
  float nb[8];
#pragma unroll
  for (int j = 0; j < 8; ++j) nb[j] = fT[(size_t)j * 256];
  for (int dd = 0; dd < 256; dd += 8) {
    float bb[8];
#pragma unroll
    for (int j = 0; j < 8; ++j) bb[j] = nb[j];
    if (dd + 8 < 256) {
#pragma unroll
      for (int j = 0; j < 8; ++j) nb[j] = fT[(size_t)(dd + 8 + j) * 256];
    }
    float4 p0 = *(const float4*)&arow[r0][dd];
    float4 p1 = *(const float4*)&arow[r0][dd + 4];
    float4 q0 = *(const float4*)&arow[r1][dd];
    float4 q1 = *(const float4*)&arow[r1][dd + 4];
    a0A += p0.x * bb[0]; a0B += p0.y * bb[1];
    a0A += p0.z * bb[2]; a0B += p0.w * bb[3];
    a0A += p1.x * bb[4]; a0B += p1.y * bb[5];
    a0A += p1.z * bb[6]; a0B += p1.w * bb[7];
    a1A += q0.x * bb[0]; a1B += q0.y * bb[1];
    a1A += q0.z * bb[2]; a1B += q0.w * bb[3];
    a1A += q1.x * bb[4]; a1B += q1.y * bb[5];
    a1A += q1.z * bb[6]; a1B += q1.w * bb[7];
  }
  float x2c = x2[b * 256 + col];
  {
    float d20 = (x2[bn0 + r0] + x2c) - 2.0f * (a0A + a0B);
    nbuf[r0][col] = -sqrtf(fmaxf(d20, 0.0f));
    float d21 = (x2[bn0 + r1] + x2c) - 2.0f * (a1A + a1B);
    nbuf[r1][col] = -sqrtf(fmaxf(d21, 0.0f));
  }
  __syncthreads();
  if (tid < 256) {
    int lane = tid & 63, w = tid >> 6;        // wave w owns row bn0+w
    float v0 = nbuf[w][lane], v1 = nbuf[w][lane + 64],
          v2 = nbuf[w][lane + 128], v3 = nbuf[w][lane + 192];
    float mx = fmaxf(fmaxf(v0, v1), fmaxf(v2, v3));
#pragma unroll
    for (int off = 32; off > 0; off >>= 1) mx = fmaxf(mx, __shfl_xor(mx, off));
    float p0 = expf(v0 - mx), p1 = expf(v1 - mx), p2 = expf(v2 - mx), p3 = expf(v3 - mx);
    double sd = (double)p0 + (double)p1 + (double)p2 + (double)p3;
#pragma unroll
    for (int off = 32; off > 0; off >>= 1) sd += __shfl_xor(sd, off);
    float denom = (float)sd;
    float s0 = p0 / denom, s1 = p1 / denom, s2 = p2 / denom, s3 = p3 / denom;
    size_t rb = (size_t)(bn0 + w) * 256;
    sim[rb + lane] = s0; sim[rb + lane + 64] = s1;
    sim[rb + lane + 128] = s2; sim[rb + lane + 192] = s3;
    float l0 = logf(s0), l1 = logf(s1), l2 = logf(s2), l3 = logf(s3);
    logits[rb + lane] = l0; logits[rb + lane + 64] = l1;
    logits[rb + lane + 128] = l2; logits[rb + lane + 192] = l3;
    int dm = (bn0 + w) & 255;
    int dj = dm >> 6, dl = dm & 63;
    float e0 = (dj == 0 && lane == dl) ? -3.4e38f : l0;
    float e1 = (dj == 1 && lane == dl) ? -3.4e38f : l1;
    float e2 = (dj == 2 && lane == dl) ? -3.4e38f : l2;
    float e3 = (dj == 3 && lane == dl) ? -3.4e38f : l3;
    float Lm = fmaxf(fmaxf(e0, e1), fmaxf(e2, e3));
#pragma unroll
    for (int off = 32; off > 0; off >>= 1) Lm = fmaxf(Lm, __shfl_xor(Lm, off));
    float lown = (dj == 0) ? l0 : (dj == 1) ? l1 : (dj == 2) ? l2 : l3;
    float l_n = __shfl(lown, dl);
    if (lane == 0) {
      laux[2 * (bn0 + w) + 0] = l_n;
      laux[2 * (bn0 + w) + 1] = Lm;
    }
  }
}

// ---------------- cand + worklist; 4 rows/block, 512 threads -----------------
__global__ __launch_bounds__(512) void cand_kernel(const float* __restrict__ sim,
                                                   const float* __restrict__ scoreT,
                                                   const int* __restrict__ edge,
                                                   const int* __restrict__ epsp,
                                                   int* __restrict__ wlist,
                                                   int* __restrict__ wcount) {
  int bn0 = blockIdx.x * 4;
  int b = bn0 >> 8;
  int tid = threadIdx.x;
  int col = tid & 255, half = tid >> 8;
  int lane = tid & 63;
  __shared__ float srow[4][256];
  {
    const float2* src = (const float2*)(sim + (size_t)bn0 * 256);
    float2 v = src[tid];
    int rr = tid >> 7, cc = (tid & 127) * 2;
    srow[rr][cc] = v.x; srow[rr][cc + 1] = v.y;
  }
  __syncthreads();
  int r0 = half * 2, r1 = r0 + 1;
  const float* sT = scoreT + (size_t)b * 65536 + col;
  float a0A = 0.f, a0B = 0.f, a1A = 0.f, a1B = 0.f;
  float nb[8];
#pragma unroll
  for (int j = 0; j < 8; ++j) nb[j] = sT[(size_t)j * 256];
  for (int kk = 0; kk < 256; kk += 8) {
    float bb[8];
#pragma unroll
    for (int j = 0; j < 8; ++j) bb[j] = nb[j];
    if (kk + 8 < 256) {
#pragma unroll
      for (int j = 0; j < 8; ++j) nb[j] = sT[(size_t)(kk + 8 + j) * 256];
    }
    float4 p0 = *(const float4*)&srow[r0][kk];
    float4 p1 = *(const float4*)&srow[r0][kk + 4];
    float4 q0 = *(const float4*)&srow[r1][kk];
    float4 q1 = *(const float4*)&srow[r1][kk + 4];
    a0A += p0.x * bb[0]; a0B += p0.y * bb[1];
    a0A += p0.z * bb[2]; a0B += p0.w * bb[3];
    a0A += p1.x * bb[4]; a0B += p1.y * bb[5];
    a0A += p1.z * bb[6]; a0B += p1.w * bb[7];
    a1A += q0.x * bb[0]; a1B += q0.y * bb[1];
    a1A += q0.z * bb[2]; a1B += q0.w * bb[3];
    a1A += q1.x * bb[4]; a1B += q1.y * bb[5];
    a1A += q1.z * bb[6]; a1B += q1.w * bb[7];
  }
  float epsv = (float)epsp[0];
  float pr[2] = {a0A + a0B, a1A + a1B};
#pragma unroll
  for (int rr = 0; rr < 2; ++rr) {
    int row = (bn0 + r0 + rr) * 256 + col;
    int em = edge[(size_t)row];
    bool active = (pr[rr] > epsv) && (em < 1);
    unsigned long long mask = __ballot(active);
    int cnt = __popcll(mask);
    int basev = 0;
    if (lane == 0 && cnt) basev = atomicAdd(wcount, cnt);
    basev = __shfl(basev, 0);
    if (active) {
      int pos = basev + __popcll(mask & ((1ull << lane) - 1ull));
      wlist[pos] = row;
    }
  }
}

// ---------------- sampling over compacted worklist + batch scatter -----------
__global__ __launch_bounds__(256) void sample_kernel(const float* __restrict__ logits,
                                                     const float* __restrict__ laux,
                                                     const int* __restrict__ wlist,
                                                     const int* __restrict__ wcount,
                                                     const int* __restrict__ edge,
                                                     const int* __restrict__ heads,
                                                     const int* __restrict__ rels,
                                                     const int* __restrict__ tails,
                                                     float* __restrict__ counts) {
  int blk = blockIdx.x;
  if (blk >= 2048) {
    int i = (blk - 2048) * 256 + threadIdx.x;  // [0, B*E)
    int b = i >> 13;                            // E = 8192
    int h = heads[i], r = rels[i], t = tails[i];
    atomicAdd(&counts[(size_t)(b * N + h) * R + r], 1.0f);
    atomicAdd(&counts[(size_t)(b * N + t) * R + r], 1.0f);
    return;
  }
  int lane = threadIdx.x & 63;
  int gw = blk * 4 + (threadIdx.x >> 6);
  int cnt = *wcount;
  for (int idx = gw; idx < cnt; idx += NSW) {
    int row = wlist[idx];
    int b = row >> 16;
    int n = (row >> 8) & 255;
    int c = row & 255;
    uint32_t base = (uint32_t)row << 8;
    float u0, u1, u2, u3;
    {
      uint32_t a0, a1;
#define GEN_U(q, dst)                                                     \
      threefry2x32_k42(0u, base + (uint32_t)((q) * 64 + lane), a0, a1);    \
      dst = __uint_as_float((((a0 ^ a1) >> 9)) | 0x3f800000u) - 1.0f;
      GEN_U(0, u0) GEN_U(1, u1) GEN_U(2, u2) GEN_U(3, u3)
#undef GEN_U
    }
    float l_n  = laux[2 * ((b << 8) + n) + 0];
    float Lmax = laux[2 * ((b << 8) + n) + 1];
    int qo = n >> 6;
    float uo = (qo == 0) ? u0 : (qo == 1) ? u1 : (qo == 2) ? u2 : u3;
    float u_n = __shfl(uo, n & 63);
    float v_n = gumbel_from_bits_f(u_n) + l_n;
    // conservative screen: u <= u_thr => g + l_k <= v_n - 0.125 + eps < v_n
    float thr_g = (v_n - Lmax) - 0.125f;
    float u_thr = expf(-expf(-thr_g));
    bool owner = (lane == (n & 63));
    bool anyc = ((u0 > u_thr) && !(owner && qo == 0)) |
                ((u1 > u_thr) && !(owner && qo == 1)) |
                ((u2 > u_thr) && !(owner && qo == 2)) |
                ((u3 > u_thr) && !(owner && qo == 3));
    if (!__any(anyc)) continue;            // argmax = n -> new_rel = 0 -> nothing

    // ---- slow path (rare): exact full argmax ----
    const float* lrow = logits + (size_t)((b << 8) + n) * N;
    float bestv = -1e30f;
    int besti = 0;
    for (int q = 0; q < 4; ++q) {
      int k = q * 64 + lane;
      uint32_t o0, o1;
      threefry2x32_k42(0u, base + (uint32_t)k, o0, o1);
      uint32_t bits = o0 ^ o1;
      float f = __uint_as_float((bits >> 9) | 0x3f800000u) - 1.0f;
      float g = gumbel_from_bits_f(f);
      float v = g + lrow[k];
      if (v > bestv || (v == bestv && k < besti)) { bestv = v; besti = k; }
    }
    for (int off = 32; off > 0; off >>= 1) {
      float ov = __shfl_down(bestv, off);
      int oi = __shfl_down(besti, off);
      if (ov > bestv || (ov == bestv && oi < besti)) { bestv = ov; besti = oi; }
    }
    if (lane == 0) {
      int nr = edge[(size_t)((b << 8) + besti) * N + c];
      if (nr != 0) {
        atomicAdd(&counts[(size_t)((b << 8) + n) * R + nr], 1.0f);
        atomicAdd(&counts[(size_t)((b << 8) + c) * R + nr], 1.0f);
      }
    }
  }
}

// ---------------- out = relu(counts @ Wr); 4 rows/block, k-split halves ------
__global__ __launch_bounds__(512) void out_kernel(const float* __restrict__ counts,
                                                  const float* __restrict__ Wr,
                                                  float* __restrict__ out) {
  int bn0 = blockIdx.x * 4;
  int tid = threadIdx.x;
  int o = tid & 255, kh = tid >> 8;
  __shared__ float crow[4][512];
  __shared__ float part[2][4][256];
  {
    const float4* src = (const float4*)(counts + (size_t)bn0 * 512);
    float4 v = src[tid];
    int rr = tid >> 7, cc = (tid & 127) * 4;
    *(float4*)&crow[rr][cc] = v;
  }
  __syncthreads();
  const float* wp = Wr + (size_t)kh * 256 * 256 + o;
  const int kbase = kh * 256;
  float accA[4] = {0, 0, 0, 0}, accB[4] = {0, 0, 0, 0};
  float nb[8];
#pragma unroll
  for (int j = 0; j < 8; ++j) nb[j] = wp[(size_t)j * 256];
  for (int k = 0; k < 256; k += 8) {
    float bb[8];
#pragma unroll
    for (int j = 0; j < 8; ++j) bb[j] = nb[j];
    if (k + 8 < 256) {
#pragma unroll
      for (int j = 0; j < 8; ++j) nb[j] = wp[(size_t)(k + 8 + j) * 256];
    }
#pragma unroll
    for (int r = 0; r < 4; ++r) {
      float4 c0 = *(const float4*)&crow[r][kbase + k];
      float4 c1 = *(const float4*)&crow[r][kbase + k + 4];
      accA[r] += c0.x * bb[0]; accB[r] += c0.y * bb[1];
      accA[r] += c0.z * bb[2]; accB[r] += c0.w * bb[3];
      accA[r] += c1.x * bb[4]; accB[r] += c1.y * bb[5];
      accA[r] += c1.z * bb[6]; accB[r] += c1.w * bb[7];
    }
  }
#pragma unroll
  for (int r = 0; r < 4; ++r) part[kh][r][o] = accA[r] + accB[r];
  __syncthreads();
  if (kh == 0) {
#pragma unroll
    for (int r = 0; r < 4; ++r)
      out[(size_t)(bn0 + r) * 256 + o] = fmaxf(part[0][r][o] + part[1][r][o], 0.0f);
  }
}

extern "C" void kernel_launch(void* const* d_in, const int* in_sizes, int n_in,
                              void* d_out, int out_size, void* d_ws, size_t ws_size,
                              hipStream_t stream) {
  (void)in_sizes; (void)n_in; (void)out_size; (void)ws_size;
  const float* f2e   = (const float*)d_in[0];
  const float* score = (const float*)d_in[1];
  const float* relf  = (const float*)d_in[2];
  const float* Wk    = (const float*)d_in[3];
  const float* bk    = (const float*)d_in[4];
  // d_in[5] local_entity: unused by the reference computation
  const int* heads   = (const int*)d_in[6];
  const int* rels    = (const int*)d_in[7];
  const int* tails   = (const int*)d_in[8];
  const int* edge    = (const int*)d_in[9];
  const int* epsp    = (const int*)d_in[10];
  float* out = (float*)d_out;

  // workspace (floats): logits | sim | Wr | counts(aliases scoreT+f2eT) |
  //                     laux | x2 | wlist | wcount
  float* ws     = (float*)d_ws;
  float* logits = ws;
  float* sim    = logits + 524288;
  float* Wr     = sim + 524288;
  float* counts = Wr + 131072;
  float* scoreT = counts;                       // alias, dead after cand
  float* f2eT   = counts + 524288;              // alias, dead after sim
  float* laux   = counts + 1048576;
  float* x2     = laux + 4096;
  int*   wlist  = (int*)(x2 + 2048);
  int*   wcount = wlist + 524288;

  prep_kernel<<<772, 512, 0, stream>>>(score, scoreT, f2e, f2eT,
                                       relf, Wk, bk, Wr, x2, wcount);
  sim_kernel<<<(B * N) / 4, 512, 0, stream>>>(f2e, f2eT, x2, sim, logits, laux);
  cand_kernel<<<(B * N) / 4, 512, 0, stream>>>(sim, scoreT, edge, epsp, wlist, wcount);
  hipMemsetAsync(counts, 0, (size_t)B * N * R * sizeof(float), stream);
  sample_kernel<<<2048 + 256, 256, 0, stream>>>(logits, laux, wlist, wcount, edge,
                                                heads, rels, tails, counts);
  out_kernel<<<(B * N) / 4, 512, 0, stream>>>(counts, Wr, out);
}

// Round 6
// 217.434 us; speedup vs baseline: 1.2936x; 1.2936x over previous
//
#include <hip/hip_runtime.h>
#include <stdint.h>

// Shapes fixed by the reference setup_inputs()
#define B 8
#define N 256
#define D 256
#define O 256
#define R 512
#define E 8192
#define TR 4
#define TRO 8
#define NSW 8192              // persistent sample waves (2048 blocks x 4)
#define F32_TINY 1.17549435e-38f

// ---------------- threefry2x32, key = (0, 42) --------------------------------
__device__ __forceinline__ void threefry2x32_k42(uint32_t x0, uint32_t x1,
                                                 uint32_t& o0, uint32_t& o1) {
  const uint32_t ks0 = 0u;
  const uint32_t ks1 = 42u;
  const uint32_t ks2 = 0u ^ 42u ^ 0x1BD11BDAu;
  x0 += ks0; x1 += ks1;
#define TF_R(r) { x0 += x1; x1 = (x1 << (r)) | (x1 >> (32 - (r))); x1 ^= x0; }
  TF_R(13) TF_R(15) TF_R(26) TF_R(6)
  x0 += ks1; x1 += ks2 + 1u;
  TF_R(17) TF_R(29) TF_R(16) TF_R(24)
  x0 += ks2; x1 += ks0 + 2u;
  TF_R(13) TF_R(15) TF_R(26) TF_R(6)
  x0 += ks0; x1 += ks1 + 3u;
  TF_R(17) TF_R(29) TF_R(16) TF_R(24)
  x0 += ks1; x1 += ks2 + 4u;
  TF_R(13) TF_R(15) TF_R(26) TF_R(6)
  x0 += ks2; x1 += ks0 + 5u;
#undef TF_R
  o0 = x0; o1 = x1;
}

__device__ __forceinline__ float gumbel_from_bits_f(float f) {
  float u = (f == 0.0f) ? F32_TINY : f;
  return -logf(-logf(u));
}

// ---------------- prep: transpose + Wr GEMM + x2 + wcount=0 ------------------
// blocks 0-255: 64x64 transpose tiles (128 score, 128 f2e)
// blocks 256-383: Wr, 4 rows/block (f32 dual-chain)
// blocks 384-391: x2 rows (f64, one row/thread)
__global__ __launch_bounds__(256) void prep_kernel(const float* __restrict__ score,
                                                   float* __restrict__ scoreT,
                                                   const float* __restrict__ f2e,
                                                   float* __restrict__ f2eT,
                                                   const float* __restrict__ relf,
                                                   const float* __restrict__ Wk,
                                                   const float* __restrict__ bk,
                                                   float* __restrict__ Wr,
                                                   float* __restrict__ x2,
                                                   int* __restrict__ wcount) {
  int blk = blockIdx.x;
  int tid = threadIdx.x;
  if (blk == 0 && tid == 0) *wcount = 0;
  if (blk < 256) {
    __shared__ float tile[64][65];
    const float* src = (blk < 128) ? score : f2e;
    float* dst = (blk < 128) ? scoreT : f2eT;
    int b7 = blk & 127;
    int bb = b7 >> 4, t = b7 & 15, ti = t >> 2, tj = t & 3;
    size_t base = (size_t)bb * 65536;
    int c = tid & 63, r4 = tid >> 6;
#pragma unroll
    for (int rr = 0; rr < 64; rr += 4) {
      int row = rr + r4;
      tile[row][c] = src[base + (size_t)(ti * 64 + row) * 256 + tj * 64 + c];
    }
    __syncthreads();
#pragma unroll
    for (int rr = 0; rr < 64; rr += 4) {
      int row = rr + r4;
      dst[base + (size_t)(tj * 64 + row) * 256 + ti * 64 + c] = tile[c][row];
    }
  } else if (blk < 384) {
    __shared__ float rrow[TR][D];
    int r0 = (blk - 256) * TR;
    int o = tid;
#pragma unroll
    for (int r = 0; r < TR; ++r) rrow[r][o] = relf[(size_t)(r0 + r) * D + o];
    __syncthreads();
    float accA[TR] = {0, 0, 0, 0}, accB[TR] = {0, 0, 0, 0};
    for (int d = 0; d < D; d += 4) {
      float w0 = Wk[(size_t)(d + 0) * O + o];
      float w1 = Wk[(size_t)(d + 1) * O + o];
      float w2 = Wk[(size_t)(d + 2) * O + o];
      float w3 = Wk[(size_t)(d + 3) * O + o];
#pragma unroll
      for (int r = 0; r < TR; ++r) {
        float4 a = *(const float4*)&rrow[r][d];
        accA[r] += a.x * w0; accB[r] += a.y * w1;
        accA[r] += a.z * w2; accB[r] += a.w * w3;
      }
    }
    float bv = bk[o];
#pragma unroll
    for (int r = 0; r < TR; ++r)
      Wr[(size_t)(r0 + r) * O + o] = (accA[r] + accB[r]) + bv;
  } else {
    // x2 rows (f64 chain keeps diag behavior stable; cheap)
    int i = (blk - 384) * 256 + tid;          // [0, 2048)
    const float4* p = (const float4*)(f2e + (size_t)i * D);
    double s = 0.0;
    for (int d = 0; d < D / 4; ++d) {
      float4 v = p[d];
      s += (double)v.x * v.x; s += (double)v.y * v.y;
      s += (double)v.z * v.z; s += (double)v.w * v.w;
    }
    x2[i] = (float)s;
  }
}

// ---------------- sim + logits + laux; 4 rows/block, 256 threads -------------
__global__ __launch_bounds__(256) void sim_kernel(const float* __restrict__ f2e,
                                                  const float* __restrict__ f2eT,
                                                  const float* __restrict__ x2,
                                                  float* __restrict__ sim,
                                                  float* __restrict__ logits,
                                                  float* __restrict__ laux) {
  int bn0 = blockIdx.x * TR;    // 4 consecutive (b,n) rows, same b
  int b = bn0 >> 8;
  int tid = threadIdx.x, lane = tid & 63, w = tid >> 6;
  __shared__ float arow[TR][256];
  __shared__ float nbuf[TR][256];
#pragma unroll
  for (int r = 0; r < TR; ++r) arow[r][tid] = f2e[(size_t)(bn0 + r) * 256 + tid];
  __syncthreads();
  float aA[TR] = {0, 0, 0, 0}, aB[TR] = {0, 0, 0, 0};
  const float* fT = f2eT + (size_t)b * 65536 + tid;
  for (int dd = 0; dd < 256; dd += 4) {
    float b0 = fT[(size_t)(dd + 0) * 256];
    float b1 = fT[(size_t)(dd + 1) * 256];
    float b2 = fT[(size_t)(dd + 2) * 256];
    float b3 = fT[(size_t)(dd + 3) * 256];
#pragma unroll
    for (int r = 0; r < TR; ++r) {
      float4 a = *(const float4*)&arow[r][dd];
      aA[r] += a.x * b0; aB[r] += a.y * b1;
      aA[r] += a.z * b2; aB[r] += a.w * b3;
    }
  }
  float x2c = x2[b * 256 + tid];
#pragma unroll
  for (int r = 0; r < TR; ++r) {
    float d2 = (x2[bn0 + r] + x2c) - 2.0f * (aA[r] + aB[r]);
    nbuf[r][tid] = -sqrtf(fmaxf(d2, 0.0f));
  }
  __syncthreads();
  // wave w owns row bn0+w: softmax + logits + laux
  float v0 = nbuf[w][lane], v1 = nbuf[w][lane + 64],
        v2 = nbuf[w][lane + 128], v3 = nbuf[w][lane + 192];
  float mx = fmaxf(fmaxf(v0, v1), fmaxf(v2, v3));
#pragma unroll
  for (int off = 32; off > 0; off >>= 1) mx = fmaxf(mx, __shfl_xor(mx, off));
  float p0 = expf(v0 - mx), p1 = expf(v1 - mx), p2 = expf(v2 - mx), p3 = expf(v3 - mx);
  double sd = (double)p0 + (double)p1 + (double)p2 + (double)p3;
#pragma unroll
  for (int off = 32; off > 0; off >>= 1) sd += __shfl_xor(sd, off);
  float denom = (float)sd;
  float s0 = p0 / denom, s1 = p1 / denom, s2 = p2 / denom, s3 = p3 / denom;
  size_t rb = (size_t)(bn0 + w) * 256;
  sim[rb + lane] = s0; sim[rb + lane + 64] = s1;
  sim[rb + lane + 128] = s2; sim[rb + lane + 192] = s3;
  float l0 = logf(s0), l1 = logf(s1), l2 = logf(s2), l3 = logf(s3);
  logits[rb + lane] = l0; logits[rb + lane + 64] = l1;
  logits[rb + lane + 128] = l2; logits[rb + lane + 192] = l3;
  int dm = (bn0 + w) & 255;
  int dj = dm >> 6, dl = dm & 63;
  float e0 = (dj == 0 && lane == dl) ? -3.4e38f : l0;
  float e1 = (dj == 1 && lane == dl) ? -3.4e38f : l1;
  float e2 = (dj == 2 && lane == dl) ? -3.4e38f : l2;
  float e3 = (dj == 3 && lane == dl) ? -3.4e38f : l3;
  float Lm = fmaxf(fmaxf(e0, e1), fmaxf(e2, e3));
#pragma unroll
  for (int off = 32; off > 0; off >>= 1) Lm = fmaxf(Lm, __shfl_xor(Lm, off));
  float lown = (dj == 0) ? l0 : (dj == 1) ? l1 : (dj == 2) ? l2 : l3;
  float l_n = __shfl(lown, dl);
  if (lane == 0) {
    laux[2 * (bn0 + w) + 0] = l_n;
    laux[2 * (bn0 + w) + 1] = Lm;
  }
}

// ---------------- cand + worklist; 4 rows/block, 256 threads -----------------
__global__ __launch_bounds__(256) void cand_kernel(const float* __restrict__ sim,
                                                   const float* __restrict__ scoreT,
                                                   const int* __restrict__ edge,
                                                   const int* __restrict__ epsp,
                                                   int* __restrict__ wlist,
                                                   int* __restrict__ wcount) {
  int bn0 = blockIdx.x * TR;
  int b = bn0 >> 8;
  int tid = threadIdx.x, lane = tid & 63;
  __shared__ float srow[TR][256];
#pragma unroll
  for (int r = 0; r < TR; ++r) srow[r][tid] = sim[(size_t)(bn0 + r) * 256 + tid];
  __syncthreads();
  float aA[TR] = {0, 0, 0, 0}, aB[TR] = {0, 0, 0, 0};
  const float* sT = scoreT + (size_t)b * 65536 + tid;
  for (int kk = 0; kk < 256; kk += 4) {
    float b0 = sT[(size_t)(kk + 0) * 256];
    float b1 = sT[(size_t)(kk + 1) * 256];
    float b2 = sT[(size_t)(kk + 2) * 256];
    float b3 = sT[(size_t)(kk + 3) * 256];
#pragma unroll
    for (int r = 0; r < TR; ++r) {
      float4 a = *(const float4*)&srow[r][kk];
      aA[r] += a.x * b0; aB[r] += a.y * b1;
      aA[r] += a.z * b2; aB[r] += a.w * b3;
    }
  }
  float epsv = (float)epsp[0];
#pragma unroll
  for (int r = 0; r < TR; ++r) {
    int row = (bn0 + r) * 256 + tid;
    int em = edge[(size_t)row];
    bool active = ((aA[r] + aB[r]) > epsv) && (em < 1);
    unsigned long long mask = __ballot(active);
    int cnt = __popcll(mask);
    int basev = 0;
    if (lane == 0 && cnt) basev = atomicAdd(wcount, cnt);
    basev = __shfl(basev, 0);
    if (active) {
      int pos = basev + __popcll(mask & ((1ull << lane) - 1ull));
      wlist[pos] = row;
    }
  }
}

// ---------------- sampling over compacted worklist + batch scatter -----------
__global__ __launch_bounds__(256) void sample_kernel(const float* __restrict__ logits,
                                                     const float* __restrict__ laux,
                                                     const int* __restrict__ wlist,
                                                     const int* __restrict__ wcount,
                                                     const int* __restrict__ edge,
                                                     const int* __restrict__ heads,
                                                     const int* __restrict__ rels,
                                                     const int* __restrict__ tails,
                                                     float* __restrict__ counts) {
  int blk = blockIdx.x;
  if (blk >= 2048) {
    int i = (blk - 2048) * 256 + threadIdx.x;  // [0, B*E)
    int b = i >> 13;                            // E = 8192
    int h = heads[i], r = rels[i], t = tails[i];
    atomicAdd(&counts[(size_t)(b * N + h) * R + r], 1.0f);
    atomicAdd(&counts[(size_t)(b * N + t) * R + r], 1.0f);
    return;
  }
  int lane = threadIdx.x & 63;
  int gw = blk * 4 + (threadIdx.x >> 6);
  int cnt = *wcount;
  for (int idx = gw; idx < cnt; idx += NSW) {
    int row = wlist[idx];
    int b = row >> 16;
    int n = (row >> 8) & 255;
    int c = row & 255;
    uint32_t base = (uint32_t)row << 8;
    float u0, u1, u2, u3;
    {
      uint32_t a0, a1;
#define GEN_U(q, dst)                                                     \
      threefry2x32_k42(0u, base + (uint32_t)((q) * 64 + lane), a0, a1);    \
      dst = __uint_as_float((((a0 ^ a1) >> 9)) | 0x3f800000u) - 1.0f;
      GEN_U(0, u0) GEN_U(1, u1) GEN_U(2, u2) GEN_U(3, u3)
#undef GEN_U
    }
    float l_n  = laux[2 * ((b << 8) + n) + 0];
    float Lmax = laux[2 * ((b << 8) + n) + 1];
    int qo = n >> 6;
    float uo = (qo == 0) ? u0 : (qo == 1) ? u1 : (qo == 2) ? u2 : u3;
    float u_n = __shfl(uo, n & 63);
    float v_n = gumbel_from_bits_f(u_n) + l_n;
    // conservative screen: u <= u_thr => g + l_k <= v_n - 0.125 + eps < v_n
    float thr_g = (v_n - Lmax) - 0.125f;
    float u_thr = expf(-expf(-thr_g));
    bool owner = (lane == (n & 63));
    bool anyc = ((u0 > u_thr) && !(owner && qo == 0)) |
                ((u1 > u_thr) && !(owner && qo == 1)) |
                ((u2 > u_thr) && !(owner && qo == 2)) |
                ((u3 > u_thr) && !(owner && qo == 3));
    if (!__any(anyc)) continue;            // argmax = n -> new_rel = 0 -> nothing

    // ---- slow path (rare): exact full argmax ----
    const float* lrow = logits + (size_t)((b << 8) + n) * N;
    float bestv = -1e30f;
    int besti = 0;
    for (int q = 0; q < 4; ++q) {
      int k = q * 64 + lane;
      uint32_t o0, o1;
      threefry2x32_k42(0u, base + (uint32_t)k, o0, o1);
      uint32_t bits = o0 ^ o1;
      float f = __uint_as_float((bits >> 9) | 0x3f800000u) - 1.0f;
      float g = gumbel_from_bits_f(f);
      float v = g + lrow[k];
      if (v > bestv || (v == bestv && k < besti)) { bestv = v; besti = k; }
    }
    for (int off = 32; off > 0; off >>= 1) {
      float ov = __shfl_down(bestv, off);
      int oi = __shfl_down(besti, off);
      if (ov > bestv || (ov == bestv && oi < besti)) { bestv = ov; besti = oi; }
    }
    if (lane == 0) {
      int nr = edge[(size_t)((b << 8) + besti) * N + c];
      if (nr != 0) {
        atomicAdd(&counts[(size_t)((b << 8) + n) * R + nr], 1.0f);
        atomicAdd(&counts[(size_t)((b << 8) + c) * R + nr], 1.0f);
      }
    }
  }
}

// ---------------- out = relu(counts @ Wr), 8 rows/block, f32 acc -------------
__global__ __launch_bounds__(256) void out_kernel(const float* __restrict__ counts,
                                                  const float* __restrict__ Wr,
                                                  float* __restrict__ out) {
  int bn0 = blockIdx.x * TRO;
  int o = threadIdx.x;
  __shared__ float crow[TRO][R];
#pragma unroll
  for (int r = 0; r < TRO; ++r) {
    crow[r][o] = counts[(size_t)(bn0 + r) * R + o];
    crow[r][o + 256] = counts[(size_t)(bn0 + r) * R + 256 + o];
  }
  __syncthreads();
  float acc[TRO] = {0, 0, 0, 0, 0, 0, 0, 0};
  for (int k = 0; k < R; k += 4) {
    float w0 = Wr[(size_t)(k + 0) * O + o];
    float w1 = Wr[(size_t)(k + 1) * O + o];
    float w2 = Wr[(size_t)(k + 2) * O + o];
    float w3 = Wr[(size_t)(k + 3) * O + o];
#pragma unroll
    for (int r = 0; r < TRO; ++r) {
      float4 cv = *(const float4*)&crow[r][k];
      acc[r] += cv.x * w0; acc[r] += cv.y * w1;
      acc[r] += cv.z * w2; acc[r] += cv.w * w3;
    }
  }
#pragma unroll
  for (int r = 0; r < TRO; ++r)
    out[(size_t)(bn0 + r) * O + o] = fmaxf(acc[r], 0.0f);
}

extern "C" void kernel_launch(void* const* d_in, const int* in_sizes, int n_in,
                              void* d_out, int out_size, void* d_ws, size_t ws_size,
                              hipStream_t stream) {
  (void)in_sizes; (void)n_in; (void)out_size; (void)ws_size;
  const float* f2e   = (const float*)d_in[0];
  const float* score = (const float*)d_in[1];
  const float* relf  = (const float*)d_in[2];
  const float* Wk    = (const float*)d_in[3];
  const float* bk    = (const float*)d_in[4];
  // d_in[5] local_entity: unused by the reference computation
  const int* heads   = (const int*)d_in[6];
  const int* rels    = (const int*)d_in[7];
  const int* tails   = (const int*)d_in[8];
  const int* edge    = (const int*)d_in[9];
  const int* epsp    = (const int*)d_in[10];
  float* out = (float*)d_out;

  // workspace (floats): logits | sim | Wr | counts(aliases scoreT+f2eT) |
  //                     laux | x2 | wlist | wcount
  float* ws     = (float*)d_ws;
  float* logits = ws;
  float* sim    = logits + 524288;
  float* Wr     = sim + 524288;
  float* counts = Wr + 131072;
  float* scoreT = counts;                       // alias, dead after cand
  float* f2eT   = counts + 524288;              // alias, dead after sim
  float* laux   = counts + 1048576;
  float* x2     = laux + 4096;
  int*   wlist  = (int*)(x2 + 2048);
  int*   wcount = wlist + 524288;

  prep_kernel<<<392, 256, 0, stream>>>(score, scoreT, f2e, f2eT,
                                       relf, Wk, bk, Wr, x2, wcount);
  sim_kernel<<<(B * N) / TR, 256, 0, stream>>>(f2e, f2eT, x2, sim, logits, laux);
  cand_kernel<<<(B * N) / TR, 256, 0, stream>>>(sim, scoreT, edge, epsp, wlist, wcount);
  hipMemsetAsync(counts, 0, (size_t)B * N * R * sizeof(float), stream);
  sample_kernel<<<2048 + 256, 256, 0, stream>>>(logits, laux, wlist, wcount, edge,
                                                heads, rels, tails, counts);
  out_kernel<<<(B * N) / TRO, 256, 0, stream>>>(counts, Wr, out);
}

// Round 7
// 204.774 us; speedup vs baseline: 1.3736x; 1.0618x over previous
//
#include <hip/hip_runtime.h>
#include <stdint.h>

// Shapes fixed by the reference setup_inputs()
#define B 8
#define N 256
#define D 256
#define O 256
#define R 512
#define E 8192
#define TRO 4
#define NSW 8192              // persistent sample waves (2048 blocks x 4)
#define F32_TINY 1.17549435e-38f

// ---------------- threefry2x32, key = (0, 42) --------------------------------
__device__ __forceinline__ void threefry2x32_k42(uint32_t x0, uint32_t x1,
                                                 uint32_t& o0, uint32_t& o1) {
  const uint32_t ks0 = 0u;
  const uint32_t ks1 = 42u;
  const uint32_t ks2 = 0u ^ 42u ^ 0x1BD11BDAu;
  x0 += ks0; x1 += ks1;
#define TF_R(r) { x0 += x1; x1 = (x1 << (r)) | (x1 >> (32 - (r))); x1 ^= x0; }
  TF_R(13) TF_R(15) TF_R(26) TF_R(6)
  x0 += ks1; x1 += ks2 + 1u;
  TF_R(17) TF_R(29) TF_R(16) TF_R(24)
  x0 += ks2; x1 += ks0 + 2u;
  TF_R(13) TF_R(15) TF_R(26) TF_R(6)
  x0 += ks0; x1 += ks1 + 3u;
  TF_R(17) TF_R(29) TF_R(16) TF_R(24)
  x0 += ks1; x1 += ks2 + 4u;
  TF_R(13) TF_R(15) TF_R(26) TF_R(6)
  x0 += ks2; x1 += ks0 + 5u;
#undef TF_R
  o0 = x0; o1 = x1;
}

__device__ __forceinline__ float gumbel_from_bits_f(float f) {
  float u = (f == 0.0f) ? F32_TINY : f;
  return -logf(-logf(u));
}

// ---------------- prep: transpose + Wr GEMM + x2 + wcount=0 ------------------
// blocks 0-255: 64x64 transpose tiles (128 score, 128 f2e)
// blocks 256-511: Wr, 2 rows/block
// blocks 512-519: x2 rows (f64, one row/thread)
__global__ __launch_bounds__(256) void prep_kernel(const float* __restrict__ score,
                                                   float* __restrict__ scoreT,
                                                   const float* __restrict__ f2e,
                                                   float* __restrict__ f2eT,
                                                   const float* __restrict__ relf,
                                                   const float* __restrict__ Wk,
                                                   const float* __restrict__ bk,
                                                   float* __restrict__ Wr,
                                                   float* __restrict__ x2,
                                                   int* __restrict__ wcount) {
  int blk = blockIdx.x;
  int tid = threadIdx.x;
  if (blk == 0 && tid == 0) *wcount = 0;
  if (blk < 256) {
    __shared__ float tile[64][65];
    const float* src = (blk < 128) ? score : f2e;
    float* dst = (blk < 128) ? scoreT : f2eT;
    int b7 = blk & 127;
    int bb = b7 >> 4, t = b7 & 15, ti = t >> 2, tj = t & 3;
    size_t base = (size_t)bb * 65536;
    int c = tid & 63, r4 = tid >> 6;
#pragma unroll
    for (int rr = 0; rr < 64; rr += 4) {
      int row = rr + r4;
      tile[row][c] = src[base + (size_t)(ti * 64 + row) * 256 + tj * 64 + c];
    }
    __syncthreads();
#pragma unroll
    for (int rr = 0; rr < 64; rr += 4) {
      int row = rr + r4;
      dst[base + (size_t)(tj * 64 + row) * 256 + ti * 64 + c] = tile[c][row];
    }
  } else if (blk < 512) {
    __shared__ float rrow[2][D];
    int r0 = (blk - 256) * 2;
    int o = tid;
#pragma unroll
    for (int r = 0; r < 2; ++r) rrow[r][o] = relf[(size_t)(r0 + r) * D + o];
    __syncthreads();
    float aA0 = 0.f, aB0 = 0.f, aA1 = 0.f, aB1 = 0.f;
    for (int d = 0; d < D; d += 4) {
      float w0 = Wk[(size_t)(d + 0) * O + o];
      float w1 = Wk[(size_t)(d + 1) * O + o];
      float w2 = Wk[(size_t)(d + 2) * O + o];
      float w3 = Wk[(size_t)(d + 3) * O + o];
      float4 a0 = *(const float4*)&rrow[0][d];
      float4 a1 = *(const float4*)&rrow[1][d];
      aA0 += a0.x * w0; aB0 += a0.y * w1; aA0 += a0.z * w2; aB0 += a0.w * w3;
      aA1 += a1.x * w0; aB1 += a1.y * w1; aA1 += a1.z * w2; aB1 += a1.w * w3;
    }
    float bv = bk[o];
    Wr[(size_t)r0 * O + o] = (aA0 + aB0) + bv;
    Wr[(size_t)(r0 + 1) * O + o] = (aA1 + aB1) + bv;
  } else {
    // x2 rows (f64 chain keeps diag behavior stable; cheap)
    int i = (blk - 512) * 256 + tid;          // [0, 2048)
    const float4* p = (const float4*)(f2e + (size_t)i * D);
    double s = 0.0;
    for (int d = 0; d < D / 4; ++d) {
      float4 v = p[d];
      s += (double)v.x * v.x; s += (double)v.y * v.y;
      s += (double)v.z * v.z; s += (double)v.w * v.w;
    }
    x2[i] = (float)s;
  }
}

// ------- fused sim + softmax + logits + laux + prob + cand + worklist --------
// One block per 2 consecutive (b,n) rows; 1024 blocks, 256 threads.
__global__ __launch_bounds__(256) void simcand_kernel(const float* __restrict__ f2e,
                                                      const float* __restrict__ f2eT,
                                                      const float* __restrict__ x2,
                                                      const float* __restrict__ scoreT,
                                                      const int* __restrict__ edge,
                                                      const int* __restrict__ epsp,
                                                      float* __restrict__ logits,
                                                      float* __restrict__ laux,
                                                      int* __restrict__ wlist,
                                                      int* __restrict__ wcount) {
  int bn0 = blockIdx.x * 2;     // rows bn0, bn0+1 (same batch: 256 is even)
  int b = bn0 >> 8;
  int tid = threadIdx.x, lane = tid & 63, w = tid >> 6;
  __shared__ float arow[2][256];
  __shared__ float simrow[2][256];
  __shared__ float wred[2][4];
  __shared__ double dred[2][4];
  __shared__ float lnsh[2];
  arow[0][tid] = f2e[(size_t)bn0 * 256 + tid];
  arow[1][tid] = f2e[(size_t)(bn0 + 1) * 256 + tid];
  __syncthreads();
  // Gram row-pair: thread = column m
  float aA0 = 0.f, aB0 = 0.f, aA1 = 0.f, aB1 = 0.f;
  const float* fT = f2eT + (size_t)b * 65536 + tid;
  for (int dd = 0; dd < 256; dd += 4) {
    float b0 = fT[(size_t)(dd + 0) * 256];
    float b1 = fT[(size_t)(dd + 1) * 256];
    float b2 = fT[(size_t)(dd + 2) * 256];
    float b3 = fT[(size_t)(dd + 3) * 256];
    float4 a0 = *(const float4*)&arow[0][dd];
    float4 a1 = *(const float4*)&arow[1][dd];
    aA0 += a0.x * b0; aB0 += a0.y * b1; aA0 += a0.z * b2; aB0 += a0.w * b3;
    aA1 += a1.x * b0; aB1 += a1.y * b1; aA1 += a1.z * b2; aB1 += a1.w * b3;
  }
  float x2c = x2[b * 256 + tid];
  float neg0 = -sqrtf(fmaxf((x2[bn0] + x2c) - 2.0f * (aA0 + aB0), 0.0f));
  float neg1 = -sqrtf(fmaxf((x2[bn0 + 1] + x2c) - 2.0f * (aA1 + aB1), 0.0f));
  // block row-max
  float m0 = neg0, m1 = neg1;
#pragma unroll
  for (int off = 32; off > 0; off >>= 1) {
    m0 = fmaxf(m0, __shfl_xor(m0, off));
    m1 = fmaxf(m1, __shfl_xor(m1, off));
  }
  if (lane == 0) { wred[0][w] = m0; wred[1][w] = m1; }
  __syncthreads();
  float mx0 = fmaxf(fmaxf(wred[0][0], wred[0][1]), fmaxf(wred[0][2], wred[0][3]));
  float mx1 = fmaxf(fmaxf(wred[1][0], wred[1][1]), fmaxf(wred[1][2], wred[1][3]));
  float p0 = expf(neg0 - mx0), p1 = expf(neg1 - mx1);
  double s0 = (double)p0, s1 = (double)p1;
#pragma unroll
  for (int off = 32; off > 0; off >>= 1) {
    s0 += __shfl_xor(s0, off);
    s1 += __shfl_xor(s1, off);
  }
  if (lane == 0) { dred[0][w] = s0; dred[1][w] = s1; }
  __syncthreads();
  float den0 = (float)(dred[0][0] + dred[0][1] + dred[0][2] + dred[0][3]);
  float den1 = (float)(dred[1][0] + dred[1][1] + dred[1][2] + dred[1][3]);
  float sv0 = p0 / den0, sv1 = p1 / den1;
  simrow[0][tid] = sv0; simrow[1][tid] = sv1;
  float l0 = logf(sv0), l1 = logf(sv1);
  logits[(size_t)bn0 * 256 + tid] = l0;
  logits[(size_t)(bn0 + 1) * 256 + tid] = l1;
  int d0 = bn0 & 255, d1 = (bn0 + 1) & 255;
  if (tid == d0) lnsh[0] = l0;
  if (tid == d1) lnsh[1] = l1;
  float e0 = (tid == d0) ? -3.4e38f : l0;
  float e1 = (tid == d1) ? -3.4e38f : l1;
#pragma unroll
  for (int off = 32; off > 0; off >>= 1) {
    e0 = fmaxf(e0, __shfl_xor(e0, off));
    e1 = fmaxf(e1, __shfl_xor(e1, off));
  }
  if (lane == 0) { wred[0][w] = e0; wred[1][w] = e1; }
  __syncthreads();     // simrow + lnsh + wred all ready
  if (tid == 0) {
    laux[2 * bn0 + 0] = lnsh[0];
    laux[2 * bn0 + 1] = fmaxf(fmaxf(wred[0][0], wred[0][1]), fmaxf(wred[0][2], wred[0][3]));
    laux[2 * bn0 + 2] = lnsh[1];
    laux[2 * bn0 + 3] = fmaxf(fmaxf(wred[1][0], wred[1][1]), fmaxf(wred[1][2], wred[1][3]));
  }
  // prob row-pair = sim @ score^T
  float pA0 = 0.f, pB0 = 0.f, pA1 = 0.f, pB1 = 0.f;
  const float* sT = scoreT + (size_t)b * 65536 + tid;
  for (int kk = 0; kk < 256; kk += 4) {
    float b0 = sT[(size_t)(kk + 0) * 256];
    float b1 = sT[(size_t)(kk + 1) * 256];
    float b2 = sT[(size_t)(kk + 2) * 256];
    float b3 = sT[(size_t)(kk + 3) * 256];
    float4 q0 = *(const float4*)&simrow[0][kk];
    float4 q1 = *(const float4*)&simrow[1][kk];
    pA0 += q0.x * b0; pB0 += q0.y * b1; pA0 += q0.z * b2; pB0 += q0.w * b3;
    pA1 += q1.x * b0; pB1 += q1.y * b1; pA1 += q1.z * b2; pB1 += q1.w * b3;
  }
  float epsv = (float)epsp[0];
  float pr[2] = {pA0 + pB0, pA1 + pB1};
#pragma unroll
  for (int r = 0; r < 2; ++r) {
    int row = (bn0 + r) * 256 + tid;
    int em = edge[(size_t)row];
    bool active = (pr[r] > epsv) && (em < 1);
    unsigned long long mask = __ballot(active);
    int cnt = __popcll(mask);
    int basev = 0;
    if (lane == 0 && cnt) basev = atomicAdd(wcount, cnt);
    basev = __shfl(basev, 0);
    if (active) {
      int pos = basev + __popcll(mask & ((1ull << lane) - 1ull));
      wlist[pos] = row;
    }
  }
}

// ---------------- sampling over compacted worklist + batch scatter -----------
__global__ __launch_bounds__(256) void sample_kernel(const float* __restrict__ logits,
                                                     const float* __restrict__ laux,
                                                     const int* __restrict__ wlist,
                                                     const int* __restrict__ wcount,
                                                     const int* __restrict__ edge,
                                                     const int* __restrict__ heads,
                                                     const int* __restrict__ rels,
                                                     const int* __restrict__ tails,
                                                     float* __restrict__ counts) {
  int blk = blockIdx.x;
  if (blk >= 2048) {
    int i = (blk - 2048) * 256 + threadIdx.x;  // [0, B*E)
    int b = i >> 13;                            // E = 8192
    int h = heads[i], r = rels[i], t = tails[i];
    atomicAdd(&counts[(size_t)(b * N + h) * R + r], 1.0f);
    atomicAdd(&counts[(size_t)(b * N + t) * R + r], 1.0f);
    return;
  }
  int lane = threadIdx.x & 63;
  int gw = blk * 4 + (threadIdx.x >> 6);
  int cnt = *wcount;
  for (int idx = gw; idx < cnt; idx += NSW) {
    int row = wlist[idx];
    int b = row >> 16;
    int n = (row >> 8) & 255;
    int c = row & 255;
    uint32_t base = (uint32_t)row << 8;
    float u0, u1, u2, u3;
    {
      uint32_t a0, a1;
#define GEN_U(q, dst)                                                     \
      threefry2x32_k42(0u, base + (uint32_t)((q) * 64 + lane), a0, a1);    \
      dst = __uint_as_float((((a0 ^ a1) >> 9)) | 0x3f800000u) - 1.0f;
      GEN_U(0, u0) GEN_U(1, u1) GEN_U(2, u2) GEN_U(3, u3)
#undef GEN_U
    }
    float l_n  = laux[2 * ((b << 8) + n) + 0];
    float Lmax = laux[2 * ((b << 8) + n) + 1];
    int qo = n >> 6;
    float uo = (qo == 0) ? u0 : (qo == 1) ? u1 : (qo == 2) ? u2 : u3;
    float u_n = __shfl(uo, n & 63);
    float v_n = gumbel_from_bits_f(u_n) + l_n;
    // conservative screen: u <= u_thr => g + l_k <= v_n - 0.125 + eps < v_n
    float thr_g = (v_n - Lmax) - 0.125f;
    float u_thr = expf(-expf(-thr_g));
    bool owner = (lane == (n & 63));
    bool anyc = ((u0 > u_thr) && !(owner && qo == 0)) |
                ((u1 > u_thr) && !(owner && qo == 1)) |
                ((u2 > u_thr) && !(owner && qo == 2)) |
                ((u3 > u_thr) && !(owner && qo == 3));
    if (!__any(anyc)) continue;            // argmax = n -> new_rel = 0 -> nothing

    // ---- slow path (rare): exact full argmax ----
    const float* lrow = logits + (size_t)((b << 8) + n) * N;
    float bestv = -1e30f;
    int besti = 0;
    for (int q = 0; q < 4; ++q) {
      int k = q * 64 + lane;
      uint32_t o0, o1;
      threefry2x32_k42(0u, base + (uint32_t)k, o0, o1);
      uint32_t bits = o0 ^ o1;
      float f = __uint_as_float((bits >> 9) | 0x3f800000u) - 1.0f;
      float g = gumbel_from_bits_f(f);
      float v = g + lrow[k];
      if (v > bestv || (v == bestv && k < besti)) { bestv = v; besti = k; }
    }
    for (int off = 32; off > 0; off >>= 1) {
      float ov = __shfl_down(bestv, off);
      int oi = __shfl_down(besti, off);
      if (ov > bestv || (ov == bestv && oi < besti)) { bestv = ov; besti = oi; }
    }
    if (lane == 0) {
      int nr = edge[(size_t)((b << 8) + besti) * N + c];
      if (nr != 0) {
        atomicAdd(&counts[(size_t)((b << 8) + n) * R + nr], 1.0f);
        atomicAdd(&counts[(size_t)((b << 8) + c) * R + nr], 1.0f);
      }
    }
  }
}

// ---------------- out = relu(counts @ Wr), 4 rows/block, f32 acc -------------
__global__ __launch_bounds__(256) void out_kernel(const float* __restrict__ counts,
                                                  const float* __restrict__ Wr,
                                                  float* __restrict__ out) {
  int bn0 = blockIdx.x * TRO;
  int o = threadIdx.x;
  __shared__ float crow[TRO][R];
#pragma unroll
  for (int r = 0; r < TRO; ++r) {
    crow[r][o] = counts[(size_t)(bn0 + r) * R + o];
    crow[r][o + 256] = counts[(size_t)(bn0 + r) * R + 256 + o];
  }
  __syncthreads();
  float accA[TRO] = {0, 0, 0, 0}, accB[TRO] = {0, 0, 0, 0};
  for (int k = 0; k < R; k += 4) {
    float w0 = Wr[(size_t)(k + 0) * O + o];
    float w1 = Wr[(size_t)(k + 1) * O + o];
    float w2 = Wr[(size_t)(k + 2) * O + o];
    float w3 = Wr[(size_t)(k + 3) * O + o];
#pragma unroll
    for (int r = 0; r < TRO; ++r) {
      float4 cv = *(const float4*)&crow[r][k];
      accA[r] += cv.x * w0; accB[r] += cv.y * w1;
      accA[r] += cv.z * w2; accB[r] += cv.w * w3;
    }
  }
#pragma unroll
  for (int r = 0; r < TRO; ++r)
    out[(size_t)(bn0 + r) * O + o] = fmaxf(accA[r] + accB[r], 0.0f);
}

extern "C" void kernel_launch(void* const* d_in, const int* in_sizes, int n_in,
                              void* d_out, int out_size, void* d_ws, size_t ws_size,
                              hipStream_t stream) {
  (void)in_sizes; (void)n_in; (void)out_size; (void)ws_size;
  const float* f2e   = (const float*)d_in[0];
  const float* score = (const float*)d_in[1];
  const float* relf  = (const float*)d_in[2];
  const float* Wk    = (const float*)d_in[3];
  const float* bk    = (const float*)d_in[4];
  // d_in[5] local_entity: unused by the reference computation
  const int* heads   = (const int*)d_in[6];
  const int* rels    = (const int*)d_in[7];
  const int* tails   = (const int*)d_in[8];
  const int* edge    = (const int*)d_in[9];
  const int* epsp    = (const int*)d_in[10];
  float* out = (float*)d_out;

  // workspace (floats): logits | Wr | counts(aliases scoreT+f2eT) |
  //                     laux | x2 | wlist | wcount
  float* ws     = (float*)d_ws;
  float* logits = ws;
  float* Wr     = logits + 524288;
  float* counts = Wr + 131072;
  float* scoreT = counts;                       // alias, dead after simcand
  float* f2eT   = counts + 524288;              // alias, dead after simcand
  float* laux   = counts + 1048576;
  float* x2     = laux + 4096;
  int*   wlist  = (int*)(x2 + 2048);
  int*   wcount = wlist + 524288;

  prep_kernel<<<520, 256, 0, stream>>>(score, scoreT, f2e, f2eT,
                                       relf, Wk, bk, Wr, x2, wcount);
  simcand_kernel<<<(B * N) / 2, 256, 0, stream>>>(f2e, f2eT, x2, scoreT, edge, epsp,
                                                  logits, laux, wlist, wcount);
  hipMemsetAsync(counts, 0, (size_t)B * N * R * sizeof(float), stream);
  sample_kernel<<<2048 + 256, 256, 0, stream>>>(logits, laux, wlist, wcount, edge,
                                                heads, rels, tails, counts);
  out_kernel<<<(B * N) / TRO, 256, 0, stream>>>(counts, Wr, out);
}